// Round 11
// baseline (40478.580 us; speedup 1.0000x reference)
//
#include <hip/hip_runtime.h>

#define HID    512
#define TPB    512
#define NSTEP  60
#define BMI    64
#define RSTRIDE 65664   // per-slice state region stride in ushorts: 2048*32 + 128 (256B pad)

using f32x4 = __attribute__((ext_vector_type(4))) float;
using s16x8 = __attribute__((ext_vector_type(8))) short;

__device__ __forceinline__ unsigned short f2bf(float f) {
    unsigned u = __builtin_bit_cast(unsigned, f);
    u += 0x7fffu + ((u >> 16) & 1u);
    return (unsigned short)(u >> 16);
}
__device__ __forceinline__ float bf2f(unsigned u) {
    return __builtin_bit_cast(float, u << 16);
}
__device__ __forceinline__ float sigm(float x) { return 1.0f / (1.0f + __expf(-x)); }
__device__ __forceinline__ float tanh_(float x) { return 1.0f - 2.0f / (__expf(2.0f * x) + 1.0f); }

// ---------------- weight packing (identical to r10 — verified) ----------------
__global__ void pack_kernel(const float* __restrict__ w_hh0, const float* __restrict__ w_ih1,
                            const float* __restrict__ w_hh1, const float* __restrict__ w_init_h,
                            const float* __restrict__ w_init_c,
                            const float* __restrict__ b_ih0, const float* __restrict__ b_hh0,
                            const float* __restrict__ b_ih1, const float* __restrict__ b_hh1,
                            unsigned short* __restrict__ PW1, unsigned short* __restrict__ PW2,
                            unsigned short* __restrict__ PI,
                            float* __restrict__ b1, float* __restrict__ b2)
{
    int idx = blockIdx.x * 256 + threadIdx.x;
    if (idx < 1048576) {
        int el = idx & 511, fr = idx >> 9;
        int ks = fr & 15, ct = (fr >> 4) & 7, s = fr >> 7;
        int lane = el >> 3, e = el & 7;
        int l15 = lane & 15;
        int gcol = (l15 & 3) * 512 + s * 32 + ct * 4 + (l15 >> 2);
        int k = ks * 32 + (lane >> 4) * 8 + e;
        PW1[idx] = f2bf(w_hh0[gcol * 512 + k]);
        return;
    }
    int i2 = idx - 1048576;
    if (i2 >= 0 && i2 < 2097152) {
        int el = i2 & 511, fr = i2 >> 9;
        int ks = fr & 31, ct = (fr >> 5) & 7, s = fr >> 8;
        int lane = el >> 3, e = el & 7;
        int l15 = lane & 15;
        int gcol = (l15 & 3) * 512 + s * 32 + ct * 4 + (l15 >> 2);
        int kk = (ks & 15) * 32 + (lane >> 4) * 8 + e;
        float v = (ks < 16) ? w_ih1[gcol * 512 + kk] : w_hh1[gcol * 512 + kk];
        PW2[i2] = f2bf(v);
        return;
    }
    int i3 = idx - (1048576 + 2097152);
    if (i3 >= 0 && i3 < 524288) {
        int el = i3 & 511, fr = i3 >> 9;
        int ks = fr & 15, tile = fr >> 4;
        int s = tile >> 5, c = tile & 31;
        int lane = el >> 3, e = el & 7;
        int n = c * 16 + (lane & 15);
        int k = ks * 32 + (lane >> 4) * 8 + e;
        float v = s ? w_init_c[n * 512 + k] : w_init_h[n * 512 + k];
        PI[i3] = f2bf(v);
        return;
    }
    int i4 = idx - (1048576 + 2097152 + 524288);
    if (i4 >= 0 && i4 < 2048) b1[i4] = b_ih0[i4] + b_hh0[i4];
    else if (i4 >= 2048 && i4 < 4096) b2[i4 - 2048] = b_ih1[i4 - 2048] + b_hh1[i4 - 2048];
}

// ---------------- init: writes padded block-major state [region b=g*16+s][row2048][col32] ----------------
__global__ __launch_bounds__(TPB, 2) void init_kernel(
    const float* __restrict__ hin, const unsigned short* __restrict__ PI,
    const float* __restrict__ b_init_h, const float* __restrict__ b_init_c,
    unsigned short* __restrict__ h1s, unsigned short* __restrict__ h2s,
    unsigned short* __restrict__ c1s, unsigned short* __restrict__ c2s)
{
    __shared__ unsigned short bufA[BMI * HID];
    const int tid = threadIdx.x, lane = tid & 63, wave = tid >> 6;
    const int m0 = blockIdx.x * BMI;
    const int l15 = lane & 15, lg = lane >> 4;
    const int swz = (lane & 7) << 4;

    for (int j = 0; j < 16; ++j) {
        int e = tid * 4 + j * 2048;
        int row = e >> 9, col = e & 511;
        float4 v = *(const float4*)(hin + (size_t)(m0 + row) * HID + col);
        ushort4 w;
        w.x = f2bf(v.x); w.y = f2bf(v.y); w.z = f2bf(v.z); w.w = f2bf(v.w);
        int L = (row * 1024 + col * 2) ^ ((row & 7) << 4);
        *(ushort4*)((char*)bufA + L) = w;
    }
    __syncthreads();

    #pragma unroll 1
    for (int cc = 0; cc < 4; ++cc) {
        int c = wave * 4 + cc;
        int nc = c * 16 + l15;
        f32x4 acc[4][2];
        #pragma unroll
        for (int rt = 0; rt < 4; ++rt)
            #pragma unroll
            for (int s = 0; s < 2; ++s)
                #pragma unroll
                for (int r = 0; r < 4; ++r) acc[rt][s][r] = 0.0f;

        #pragma unroll
        for (int ks = 0; ks < 16; ++ks) {
            s16x8 a[4];
            #pragma unroll
            for (int rt = 0; rt < 4; ++rt) {
                int ao = (rt * 16 + l15) * 1024 + ((ks * 64 + lg * 16) ^ swz);
                a[rt] = *(const s16x8*)((const char*)bufA + ao);
            }
            #pragma unroll
            for (int s = 0; s < 2; ++s) {
                s16x8 b = ((const s16x8*)PI)[((s * 32 + c) * 16 + ks) * 64 + lane];
                #pragma unroll
                for (int rt = 0; rt < 4; ++rt)
                    acc[rt][s] = __builtin_amdgcn_mfma_f32_16x16x32_bf16(a[rt], b, acc[rt][s], 0, 0, 0);
            }
        }
        float bh = b_init_h[nc], bc = b_init_c[nc];
        #pragma unroll
        for (int rt = 0; rt < 4; ++rt)
            #pragma unroll
            for (int r = 0; r < 4; ++r) {
                int m = m0 + rt * 16 + lg * 4 + r;
                float hv = acc[rt][0][r] + bh;
                float cv = acc[rt][1][r] + bc;
                unsigned short hb = f2bf(hv);
                size_t o = (size_t)((m >> 11) * 16 + (nc >> 5)) * RSTRIDE
                         + (size_t)(m & 2047) * 32 + (nc & 31);
                h1s[o] = hb; h2s[o] = hb;
                c1s[o] = f2bf(cv); c2s[o] = f2bf(cv);
            }
    }
}

// ---------------- layer-1: per-wave full-K, LDS transpose epilogue, block-major state ----------------
__global__ __launch_bounds__(TPB, 2) void l1_kernel(
    const unsigned short* __restrict__ h1R, unsigned short* __restrict__ h1W,
    unsigned short* __restrict__ c1s, const float* __restrict__ pp,
    float* __restrict__ outp, const unsigned short* __restrict__ PW1,
    const float* __restrict__ b1, const float* __restrict__ w_ih0,
    const float* __restrict__ b_out, int t)
{
    __shared__ __align__(16) unsigned short Ab[2 * 16384];  // 2 x 32 KB
    __shared__ __align__(16) float xls[4096];               // 16 KB
    __shared__ __align__(16) float tsc[8 * 320];            // 10 KB

    const int tid = threadIdx.x, lane = tid & 63, w = tid >> 6;
    const int b = blockIdx.x;
    const int g = 2 * (b & 7) + (b >> 7);
    const int s = (b >> 3) & 15;
    const int m0 = g * 2048;
    const int l15 = lane & 15, lg = lane >> 4;
    const int q = l15 & 3, a = l15 >> 2;
    const int ct = w;
    const int hid = s * 32 + ct * 4 + a;
    float* const ts = tsc + w * 320;
    const size_t myReg = (size_t)(g * 16 + s) * RSTRIDE;      // own c1/h1W region
    const int myCol = ct * 4 + a;

    s16x8 bw[16];
    #pragma unroll
    for (int ks = 0; ks < 16; ++ks)
        bw[ks] = ((const s16x8*)PW1)[((s * 8 + ct) * 16 + ks) * 64 + lane];

    float b1v[4], wiA[4], wiB[4];
    #pragma unroll
    for (int k = 0; k < 4; ++k) {
        int gc = k * 512 + hid;
        b1v[k] = b1[gc];
        wiA[k] = w_ih0[gc * 2 + 0];
        wiB[k] = w_ih0[gc * 2 + 1];
    }
    float bo0 = b_out[0], bo1 = b_out[1];

    // ---- reduce prev-step partials -> xls; write out[:,t-1] ----
    if (t == 0) {
        #pragma unroll
        for (int i = 0; i < 8; ++i) xls[tid * 8 + i] = 0.0f;
    } else {
        f32x4 s0 = {0.f,0.f,0.f,0.f}, s1 = {0.f,0.f,0.f,0.f};
        #pragma unroll 1
        for (int ss = 0; ss < 16; ++ss) {
            const float* p = pp + (((size_t)(g * 16 + ss)) << 12) + tid * 8;
            s0 += *(const f32x4*)p;
            s1 += *(const f32x4*)(p + 4);
        }
        s0[0] += bo0; s0[1] += bo1; s0[2] += bo0; s0[3] += bo1;
        s1[0] += bo0; s1[1] += bo1; s1[2] += bo0; s1[3] += bo1;
        *(f32x4*)(xls + tid * 8) = s0;
        *(f32x4*)(xls + tid * 8 + 4) = s1;
        if (s == 0) {
            float* ob = outp + (size_t)(m0 + tid * 4) * (2 * NSTEP) + (t - 1) * 2;
            *(float2*)(ob)             = make_float2(s0[0], s0[1]);
            *(float2*)(ob + 2 * NSTEP) = make_float2(s0[2], s0[3]);
            *(float2*)(ob + 4 * NSTEP) = make_float2(s1[0], s1[1]);
            *(float2*)(ob + 6 * NSTEP) = make_float2(s1[2], s1[3]);
        }
    }

    // staging decompose: thread -> (ks quarter, row32, lgq); src 16B from region ks, 2KB contiguous runs
    const int st_ks4 = tid >> 7;            // ks = p*4 + st_ks4
    const int st_row = (tid >> 2) & 31;
    const int st_lgq = tid & 3;
    const size_t gR = (size_t)(g * 16);

    // prologue: stage chunk 0 into buf0; load chunk 1 into nv; prefetch c(0)
    uint4 nv[4];
    #pragma unroll
    for (int p = 0; p < 4; ++p) {
        int ks = p * 4 + st_ks4;
        uint4 v = *(const uint4*)(h1R + (gR + ks) * RSTRIDE + (size_t)st_row * 32 + st_lgq * 8);
        *(uint4*)((char*)Ab + ks * 2048 + (st_row >> 4) * 1024 + st_lgq * 256 + (st_row & 15) * 16) = v;
    }
    #pragma unroll
    for (int p = 0; p < 4; ++p) {
        int ks = p * 4 + st_ks4;
        nv[p] = *(const uint4*)(h1R + (gR + ks) * RSTRIDE + (size_t)(32 + st_row) * 32 + st_lgq * 8);
    }
    unsigned short cpr0 = c1s[myReg + (size_t)(lg * 4 + q) * 32 + myCol];
    unsigned short cpr1 = c1s[myReg + (size_t)(16 + lg * 4 + q) * 32 + myCol];
    __syncthreads();

    #pragma unroll 1
    for (int ch = 0; ch < 64; ++ch) {
        if (ch < 63) {
            char* AbW = (char*)Ab + ((ch + 1) & 1) * 32768;
            #pragma unroll
            for (int p = 0; p < 4; ++p) {
                int ks = p * 4 + st_ks4;
                *(uint4*)(AbW + ks * 2048 + (st_row >> 4) * 1024 + st_lgq * 256 + (st_row & 15) * 16) = nv[p];
            }
        }
        if (ch < 62) {
            #pragma unroll
            for (int p = 0; p < 4; ++p) {
                int ks = p * 4 + st_ks4;
                nv[p] = *(const uint4*)(h1R + (gR + ks) * RSTRIDE + (size_t)((ch + 2) * 32 + st_row) * 32 + st_lgq * 8);
            }
        }
        unsigned short cnx0 = 0, cnx1 = 0;
        if (ch < 63) {
            cnx0 = c1s[myReg + (size_t)((ch + 1) * 32 + lg * 4 + q) * 32 + myCol];
            cnx1 = c1s[myReg + (size_t)((ch + 1) * 32 + 16 + lg * 4 + q) * 32 + myCol];
        }

        const char* AbR = (const char*)Ab + (ch & 1) * 32768;
        f32x4 a0A = {0.f,0.f,0.f,0.f}, a0B = {0.f,0.f,0.f,0.f};
        f32x4 a1A = {0.f,0.f,0.f,0.f}, a1B = {0.f,0.f,0.f,0.f};
        #pragma unroll
        for (int ksl = 0; ksl < 8; ++ksl) {
            s16x8 x0 = *(const s16x8*)(AbR + ksl * 2048 + lane * 16);
            s16x8 x1 = *(const s16x8*)(AbR + ksl * 2048 + 1024 + lane * 16);
            a0A = __builtin_amdgcn_mfma_f32_16x16x32_bf16(x0, bw[ksl], a0A, 0, 0, 0);
            a1A = __builtin_amdgcn_mfma_f32_16x16x32_bf16(x1, bw[ksl], a1A, 0, 0, 0);
        }
        #pragma unroll
        for (int ksl = 8; ksl < 16; ++ksl) {
            s16x8 x0 = *(const s16x8*)(AbR + ksl * 2048 + lane * 16);
            s16x8 x1 = *(const s16x8*)(AbR + ksl * 2048 + 1024 + lane * 16);
            a0B = __builtin_amdgcn_mfma_f32_16x16x32_bf16(x0, bw[ksl], a0B, 0, 0, 0);
            a1B = __builtin_amdgcn_mfma_f32_16x16x32_bf16(x1, bw[ksl], a1B, 0, 0, 0);
        }
        f32x4 acS0 = a0A + a0B, acS1 = a1A + a1B;

        #pragma unroll
        for (int rh = 0; rh < 2; ++rh) {
            f32x4 ac = rh ? acS1 : acS0;
            #pragma unroll
            for (int r = 0; r < 4; ++r)
                ts[(lg * 4 + r) * 20 + l15] = ac[r];
            f32x4 gq = *(const f32x4*)(ts + (lg * 4 + q) * 20 + a * 4);

            int grow = ch * 32 + rh * 16 + lg * 4 + q;
            float2 xv = *(const float2*)(xls + grow * 2);
            float iv = sigm(gq[0] + b1v[0] + xv.x * wiA[0] + xv.y * wiB[0]);
            float fv = sigm(gq[1] + b1v[1] + xv.x * wiA[1] + xv.y * wiB[1]);
            float gv = tanh_(gq[2] + b1v[2] + xv.x * wiA[2] + xv.y * wiB[2]);
            float ov = sigm(gq[3] + b1v[3] + xv.x * wiA[3] + xv.y * wiB[3]);
            float cold = bf2f(rh ? cpr1 : cpr0);
            float cn = fv * cold + iv * gv;
            float hn = ov * tanh_(cn);
            size_t cix = myReg + (size_t)grow * 32 + myCol;
            c1s[cix] = f2bf(cn);
            h1W[cix] = f2bf(hn);
        }
        cpr0 = cnx0; cpr1 = cnx1;
        __syncthreads();
    }
}

// ---------------- layer-2: per-wave full-K (K=1024), block-major state ----------------
__global__ __launch_bounds__(TPB, 2) void l2_kernel(
    const unsigned short* __restrict__ h1C, const unsigned short* __restrict__ h2R,
    unsigned short* __restrict__ h2W, unsigned short* __restrict__ c2s,
    float* __restrict__ pp,
    const unsigned short* __restrict__ PW2, const float* __restrict__ b2,
    const float* __restrict__ w_out)
{
    __shared__ __align__(16) unsigned short Ab[2 * 32768];  // 2 x 64 KB
    __shared__ __align__(16) float pl[2][32][2][9];         // 4.5 KB
    __shared__ __align__(16) float tsc[8 * 320];            // 10 KB

    const int tid = threadIdx.x, lane = tid & 63, w = tid >> 6;
    const int b = blockIdx.x;
    const int g = 2 * (b & 7) + (b >> 7);
    const int s = (b >> 3) & 15;
    const int l15 = lane & 15, lg = lane >> 4;
    const int q = l15 & 3, a = l15 >> 2;
    const int ct = w;
    const int hid = s * 32 + ct * 4 + a;
    float* const ts = tsc + w * 320;
    const size_t myReg = (size_t)(g * 16 + s) * RSTRIDE;
    const int myCol = ct * 4 + a;

    s16x8 bw[32];
    #pragma unroll
    for (int ks = 0; ks < 32; ++ks)
        bw[ks] = ((const s16x8*)PW2)[((s * 8 + ct) * 32 + ks) * 64 + lane];

    float b2v[4];
    #pragma unroll
    for (int k = 0; k < 4; ++k) b2v[k] = b2[k * 512 + hid];
    const float wo0 = w_out[hid], wo1 = w_out[512 + hid];

    const int st_ks4 = tid >> 7;
    const int st_row = (tid >> 2) & 31;
    const int st_lgq = tid & 3;
    const size_t gR = (size_t)(g * 16);

    uint4 nv[8];
    #pragma unroll
    for (int p = 0; p < 8; ++p) {
        int ks = p * 4 + st_ks4;
        const unsigned short* src = (ks < 16) ? h1C : h2R;
        int kel = (ks < 16) ? ks : (ks - 16);
        uint4 v = *(const uint4*)(src + (gR + kel) * RSTRIDE + (size_t)st_row * 32 + st_lgq * 8);
        *(uint4*)((char*)Ab + ks * 2048 + (st_row >> 4) * 1024 + st_lgq * 256 + (st_row & 15) * 16) = v;
    }
    #pragma unroll
    for (int p = 0; p < 8; ++p) {
        int ks = p * 4 + st_ks4;
        const unsigned short* src = (ks < 16) ? h1C : h2R;
        int kel = (ks < 16) ? ks : (ks - 16);
        nv[p] = *(const uint4*)(src + (gR + kel) * RSTRIDE + (size_t)(32 + st_row) * 32 + st_lgq * 8);
    }
    unsigned short cpr0 = c2s[myReg + (size_t)(lg * 4 + q) * 32 + myCol];
    unsigned short cpr1 = c2s[myReg + (size_t)(16 + lg * 4 + q) * 32 + myCol];
    __syncthreads();

    #pragma unroll 1
    for (int ch = 0; ch < 64; ++ch) {
        if (ch < 63) {
            char* AbW = (char*)Ab + ((ch + 1) & 1) * 65536;
            #pragma unroll
            for (int p = 0; p < 8; ++p) {
                int ks = p * 4 + st_ks4;
                *(uint4*)(AbW + ks * 2048 + (st_row >> 4) * 1024 + st_lgq * 256 + (st_row & 15) * 16) = nv[p];
            }
        }
        if (ch < 62) {
            #pragma unroll
            for (int p = 0; p < 8; ++p) {
                int ks = p * 4 + st_ks4;
                const unsigned short* src = (ks < 16) ? h1C : h2R;
                int kel = (ks < 16) ? ks : (ks - 16);
                nv[p] = *(const uint4*)(src + (gR + kel) * RSTRIDE + (size_t)((ch + 2) * 32 + st_row) * 32 + st_lgq * 8);
            }
        }
        unsigned short cnx0 = 0, cnx1 = 0;
        if (ch < 63) {
            cnx0 = c2s[myReg + (size_t)((ch + 1) * 32 + lg * 4 + q) * 32 + myCol];
            cnx1 = c2s[myReg + (size_t)((ch + 1) * 32 + 16 + lg * 4 + q) * 32 + myCol];
        }

        const char* AbR = (const char*)Ab + (ch & 1) * 65536;
        f32x4 a0A = {0.f,0.f,0.f,0.f}, a0B = {0.f,0.f,0.f,0.f};
        f32x4 a1A = {0.f,0.f,0.f,0.f}, a1B = {0.f,0.f,0.f,0.f};
        #pragma unroll
        for (int ksl = 0; ksl < 16; ++ksl) {
            s16x8 x0 = *(const s16x8*)(AbR + ksl * 2048 + lane * 16);
            s16x8 x1 = *(const s16x8*)(AbR + ksl * 2048 + 1024 + lane * 16);
            a0A = __builtin_amdgcn_mfma_f32_16x16x32_bf16(x0, bw[ksl], a0A, 0, 0, 0);
            a1A = __builtin_amdgcn_mfma_f32_16x16x32_bf16(x1, bw[ksl], a1A, 0, 0, 0);
        }
        #pragma unroll
        for (int ksl = 16; ksl < 32; ++ksl) {
            s16x8 x0 = *(const s16x8*)(AbR + ksl * 2048 + lane * 16);
            s16x8 x1 = *(const s16x8*)(AbR + ksl * 2048 + 1024 + lane * 16);
            a0B = __builtin_amdgcn_mfma_f32_16x16x32_bf16(x0, bw[ksl], a0B, 0, 0, 0);
            a1B = __builtin_amdgcn_mfma_f32_16x16x32_bf16(x1, bw[ksl], a1B, 0, 0, 0);
        }
        f32x4 acS0 = a0A + a0B, acS1 = a1A + a1B;

        #pragma unroll
        for (int rh = 0; rh < 2; ++rh) {
            f32x4 ac = rh ? acS1 : acS0;
            #pragma unroll
            for (int r = 0; r < 4; ++r)
                ts[(lg * 4 + r) * 20 + l15] = ac[r];
            f32x4 gq = *(const f32x4*)(ts + (lg * 4 + q) * 20 + a * 4);

            int rloc = rh * 16 + lg * 4 + q;
            int grow = ch * 32 + rloc;
            float iv = sigm(gq[0] + b2v[0]);
            float fv = sigm(gq[1] + b2v[1]);
            float gv = tanh_(gq[2] + b2v[2]);
            float ov = sigm(gq[3] + b2v[3]);
            float cold = bf2f(rh ? cpr1 : cpr0);
            float cn = fv * cold + iv * gv;
            float hn = ov * tanh_(cn);
            size_t cix = myReg + (size_t)grow * 32 + myCol;
            c2s[cix] = f2bf(cn);
            h2W[cix] = f2bf(hn);
            float p0 = hn * wo0, p1 = hn * wo1;
            p0 += __shfl_xor(p0, 4); p0 += __shfl_xor(p0, 8);
            p1 += __shfl_xor(p1, 4); p1 += __shfl_xor(p1, 8);
            if (a == 0) {
                pl[ch & 1][rloc][0][ct] = p0;
                pl[ch & 1][rloc][1][ct] = p1;
            }
        }
        if (ch > 0 && tid < 64) {
            int row = tid >> 1, j = tid & 1;
            const float* pr = &pl[(ch - 1) & 1][row][j][0];
            float sum = pr[0] + pr[1] + pr[2] + pr[3] + pr[4] + pr[5] + pr[6] + pr[7];
            pp[((size_t)(g * 16 + s)) * 4096 + (size_t)((ch - 1) * 32 + row) * 2 + j] = sum;
        }
        cpr0 = cnx0; cpr1 = cnx1;
        __syncthreads();
    }
    if (tid < 64) {
        int row = tid >> 1, j = tid & 1;
        const float* pr = &pl[1][row][j][0];
        float sum = pr[0] + pr[1] + pr[2] + pr[3] + pr[4] + pr[5] + pr[6] + pr[7];
        pp[((size_t)(g * 16 + s)) * 4096 + (size_t)(63 * 32 + row) * 2 + j] = sum;
    }
}

// ---------------- final-step output ----------------
__global__ void tail_kernel(const float* __restrict__ pp, const float* __restrict__ b_out,
                            float* __restrict__ outp)
{
    int i = blockIdx.x * 256 + threadIdx.x;
    if (i < 65536) {
        int m = i >> 1, j = i & 1;
        int g = m >> 11;
        int idx = (m & 2047) * 2 + j;
        float sum = b_out[j];
        #pragma unroll 1
        for (int s = 0; s < 16; ++s)
            sum += pp[(((size_t)(g * 16 + s)) << 12) + idx];
        outp[(size_t)m * (2 * NSTEP) + (NSTEP - 1) * 2 + j] = sum;
    }
}

extern "C" void kernel_launch(void* const* d_in, const int* in_sizes, int n_in,
                              void* d_out, int out_size, void* d_ws, size_t ws_size,
                              hipStream_t stream)
{
    (void)in_sizes; (void)n_in; (void)out_size; (void)ws_size;
    const float* h        = (const float*)d_in[0];
    const float* w_init_h = (const float*)d_in[1];
    const float* b_init_h = (const float*)d_in[2];
    const float* w_init_c = (const float*)d_in[3];
    const float* b_init_c = (const float*)d_in[4];
    const float* w_ih0    = (const float*)d_in[5];
    const float* w_hh0    = (const float*)d_in[6];
    const float* b_ih0    = (const float*)d_in[7];
    const float* b_hh0    = (const float*)d_in[8];
    const float* w_ih1    = (const float*)d_in[9];
    const float* w_hh1    = (const float*)d_in[10];
    const float* b_ih1    = (const float*)d_in[11];
    const float* b_hh1    = (const float*)d_in[12];
    const float* w_out    = (const float*)d_in[13];
    const float* b_out    = (const float*)d_in[14];
    float* out = (float*)d_out;

    const size_t SREG = (size_t)256 * RSTRIDE * 2;   // 33,619,968 B per state array
    char* ws = (char*)d_ws;
    unsigned short* h1s[2] = { (unsigned short*)(ws + 0 * SREG),
                               (unsigned short*)(ws + 1 * SREG) };
    unsigned short* h2s[2] = { (unsigned short*)(ws + 2 * SREG),
                               (unsigned short*)(ws + 3 * SREG) };
    unsigned short* c1s = (unsigned short*)(ws + 4 * SREG);
    unsigned short* c2s = (unsigned short*)(ws + 5 * SREG);
    char* tail = ws + 6 * SREG;
    float* pp           = (float*)(tail);                       // 4 MB
    unsigned short* PW1 = (unsigned short*)(tail + 4194304);    // 2 MB
    unsigned short* PW2 = (unsigned short*)(tail + 6291456);    // 4 MB
    unsigned short* PI  = (unsigned short*)(tail + 10485760);   // 1 MB
    float* b1 = (float*)(tail + 11534336);
    float* b2 = (float*)(tail + 11542528);

    pack_kernel<<<14352, 256, 0, stream>>>(w_hh0, w_ih1, w_hh1, w_init_h, w_init_c,
                                           b_ih0, b_hh0, b_ih1, b_hh1, PW1, PW2, PI, b1, b2);
    init_kernel<<<32768 / BMI, TPB, 0, stream>>>(h, PI, b_init_h, b_init_c,
                                                 h1s[1], h2s[1], c1s, c2s);
    for (int t = 0; t < NSTEP; ++t) {
        const unsigned short* h1R = h1s[(t + 1) & 1];
        unsigned short* h1W = h1s[t & 1];
        const unsigned short* h2R = h2s[(t + 1) & 1];
        unsigned short* h2W = h2s[t & 1];
        l1_kernel<<<256, TPB, 0, stream>>>(h1R, h1W, c1s, pp, out, PW1, b1, w_ih0, b_out, t);
        l2_kernel<<<256, TPB, 0, stream>>>(h1W, h2R, h2W, c2s, pp, PW2, b2, w_out);
    }
    tail_kernel<<<256, 256, 0, stream>>>(pp, b_out, out);
}

// Round 12
// 37846.445 us; speedup vs baseline: 1.0695x; 1.0695x over previous
//
#include <hip/hip_runtime.h>

#define HID    512
#define TPB    512
#define NSTEP  60
#define BMI    64

using f32x4 = __attribute__((ext_vector_type(4))) float;
using s16x8 = __attribute__((ext_vector_type(8))) short;

__device__ __forceinline__ unsigned short f2bf(float f) {
    unsigned u = __builtin_bit_cast(unsigned, f);
    u += 0x7fffu + ((u >> 16) & 1u);
    return (unsigned short)(u >> 16);
}
__device__ __forceinline__ float bf2f(unsigned u) {
    return __builtin_bit_cast(float, u << 16);
}
__device__ __forceinline__ float sigm(float x) { return 1.0f / (1.0f + __expf(-x)); }
__device__ __forceinline__ float tanh_(float x) { return 1.0f - 2.0f / (__expf(2.0f * x) + 1.0f); }

// ---------------- weight packing (identical to r10 — verified) ----------------
// Col mapping inside each 16-col MFMA tile: col c -> gate (c&3), unit ct*4+(c>>2).
__global__ void pack_kernel(const float* __restrict__ w_hh0, const float* __restrict__ w_ih1,
                            const float* __restrict__ w_hh1, const float* __restrict__ w_init_h,
                            const float* __restrict__ w_init_c,
                            const float* __restrict__ b_ih0, const float* __restrict__ b_hh0,
                            const float* __restrict__ b_ih1, const float* __restrict__ b_hh1,
                            unsigned short* __restrict__ PW1, unsigned short* __restrict__ PW2,
                            unsigned short* __restrict__ PI,
                            float* __restrict__ b1, float* __restrict__ b2)
{
    int idx = blockIdx.x * 256 + threadIdx.x;
    if (idx < 1048576) {
        int el = idx & 511, fr = idx >> 9;
        int ks = fr & 15, ct = (fr >> 4) & 7, s = fr >> 7;
        int lane = el >> 3, e = el & 7;
        int l15 = lane & 15;
        int gcol = (l15 & 3) * 512 + s * 32 + ct * 4 + (l15 >> 2);
        int k = ks * 32 + (lane >> 4) * 8 + e;
        PW1[idx] = f2bf(w_hh0[gcol * 512 + k]);
        return;
    }
    int i2 = idx - 1048576;
    if (i2 >= 0 && i2 < 2097152) {
        int el = i2 & 511, fr = i2 >> 9;
        int ks = fr & 31, ct = (fr >> 5) & 7, s = fr >> 8;
        int lane = el >> 3, e = el & 7;
        int l15 = lane & 15;
        int gcol = (l15 & 3) * 512 + s * 32 + ct * 4 + (l15 >> 2);
        int kk = (ks & 15) * 32 + (lane >> 4) * 8 + e;
        float v = (ks < 16) ? w_ih1[gcol * 512 + kk] : w_hh1[gcol * 512 + kk];
        PW2[i2] = f2bf(v);
        return;
    }
    int i3 = idx - (1048576 + 2097152);
    if (i3 >= 0 && i3 < 524288) {
        int el = i3 & 511, fr = i3 >> 9;
        int ks = fr & 15, tile = fr >> 4;
        int s = tile >> 5, c = tile & 31;
        int lane = el >> 3, e = el & 7;
        int n = c * 16 + (lane & 15);
        int k = ks * 32 + (lane >> 4) * 8 + e;
        float v = s ? w_init_c[n * 512 + k] : w_init_h[n * 512 + k];
        PI[i3] = f2bf(v);
        return;
    }
    int i4 = idx - (1048576 + 2097152 + 524288);
    if (i4 >= 0 && i4 < 2048) b1[i4] = b_ih0[i4] + b_hh0[i4];
    else if (i4 >= 2048 && i4 < 4096) b2[i4 - 2048] = b_ih1[i4 - 2048] + b_hh1[i4 - 2048];
}

// ---------------- init (r10 version, interleaved [m][512] state — verified) ----------------
__global__ __launch_bounds__(TPB, 2) void init_kernel(
    const float* __restrict__ hin, const unsigned short* __restrict__ PI,
    const float* __restrict__ b_init_h, const float* __restrict__ b_init_c,
    unsigned short* __restrict__ h1s, unsigned short* __restrict__ h2s,
    unsigned short* __restrict__ c1s, unsigned short* __restrict__ c2s)
{
    __shared__ unsigned short bufA[BMI * HID];
    const int tid = threadIdx.x, lane = tid & 63, wave = tid >> 6;
    const int m0 = blockIdx.x * BMI;
    const int l15 = lane & 15, lg = lane >> 4;
    const int swz = (lane & 7) << 4;

    for (int j = 0; j < 16; ++j) {
        int e = tid * 4 + j * 2048;
        int row = e >> 9, col = e & 511;
        float4 v = *(const float4*)(hin + (size_t)(m0 + row) * HID + col);
        ushort4 w;
        w.x = f2bf(v.x); w.y = f2bf(v.y); w.z = f2bf(v.z); w.w = f2bf(v.w);
        int L = (row * 1024 + col * 2) ^ ((row & 7) << 4);
        *(ushort4*)((char*)bufA + L) = w;
    }
    __syncthreads();

    #pragma unroll 1
    for (int cc = 0; cc < 4; ++cc) {
        int c = wave * 4 + cc;
        int nc = c * 16 + l15;
        f32x4 acc[4][2];
        #pragma unroll
        for (int rt = 0; rt < 4; ++rt)
            #pragma unroll
            for (int s = 0; s < 2; ++s)
                #pragma unroll
                for (int r = 0; r < 4; ++r) acc[rt][s][r] = 0.0f;

        #pragma unroll
        for (int ks = 0; ks < 16; ++ks) {
            s16x8 a[4];
            #pragma unroll
            for (int rt = 0; rt < 4; ++rt) {
                int ao = (rt * 16 + l15) * 1024 + ((ks * 64 + lg * 16) ^ swz);
                a[rt] = *(const s16x8*)((const char*)bufA + ao);
            }
            #pragma unroll
            for (int s = 0; s < 2; ++s) {
                s16x8 b = ((const s16x8*)PI)[((s * 32 + c) * 16 + ks) * 64 + lane];
                #pragma unroll
                for (int rt = 0; rt < 4; ++rt)
                    acc[rt][s] = __builtin_amdgcn_mfma_f32_16x16x32_bf16(a[rt], b, acc[rt][s], 0, 0, 0);
            }
        }
        float bh = b_init_h[nc], bc = b_init_c[nc];
        #pragma unroll
        for (int rt = 0; rt < 4; ++rt)
            #pragma unroll
            for (int r = 0; r < 4; ++r) {
                int m = m0 + rt * 16 + lg * 4 + r;
                float hv = acc[rt][0][r] + bh;
                float cv = acc[rt][1][r] + bc;
                unsigned short hb = f2bf(hv);
                size_t o = (size_t)m * HID + nc;
                h1s[o] = hb; h2s[o] = hb;
                c1s[o] = f2bf(cv); c2s[o] = f2bf(cv);
            }
    }
}

// ---------------- layer-1: waves = 4 ct-pairs x 2 kh; 2-copy gl merge; 2 barriers/chunk ----------------
__global__ __launch_bounds__(TPB, 2) void l1_kernel(
    const unsigned short* __restrict__ h1R, unsigned short* __restrict__ h1W,
    unsigned short* __restrict__ c1s, const float* __restrict__ pp,
    float* __restrict__ outp, const unsigned short* __restrict__ PW1,
    const float* __restrict__ b1, const float* __restrict__ w_ih0,
    const float* __restrict__ b_out, int t)
{
    __shared__ __align__(16) unsigned short Ab[16384];   // 32 KB single buffer
    __shared__ __align__(16) float glf[2 * 4224];        // 33 KB: [kh][row32][col 132pad]
    __shared__ __align__(16) float xls[4096];            // 16 KB

    const int tid = threadIdx.x, lane = tid & 63, w = tid >> 6;
    const int b = blockIdx.x;
    const int g = 2 * (b & 7) + (b >> 7);
    const int s = (b >> 3) & 15;
    const int m0 = g * 2048;
    const int l15 = lane & 15, lg = lane >> 4;
    const int cg = w >> 1, kh = w & 1;

    // B fragments: ct = cg*2+j, ks = kh*8+ksl  (32 VGPR)
    s16x8 bw[2][8];
    #pragma unroll
    for (int j = 0; j < 2; ++j)
        #pragma unroll
        for (int ksl = 0; ksl < 8; ++ksl)
            bw[j][ksl] = ((const s16x8*)PW1)[(((s * 8 + cg * 2 + j) * 16) + kh * 8 + ksl) * 64 + lane];

    // epilogue role: row erow (0..31), units 2ejp, 2ejp+1
    const int erow = tid >> 4, ejp = tid & 15;
    float b1v[8], wiA[8], wiB[8];
    #pragma unroll
    for (int q = 0; q < 8; ++q) {
        int dj = q & 1, gq = q >> 1;
        int gcol = gq * 512 + s * 32 + ejp * 2 + dj;
        b1v[q] = b1[gcol];
        wiA[q] = w_ih0[gcol * 2 + 0];
        wiB[q] = w_ih0[gcol * 2 + 1];
    }
    float bo0 = b_out[0], bo1 = b_out[1];

    // ---- reduce prev-step partials -> xls; write out[:,t-1] ----
    if (t == 0) {
        #pragma unroll
        for (int i = 0; i < 8; ++i) xls[tid * 8 + i] = 0.0f;
    } else {
        f32x4 s0 = {0.f,0.f,0.f,0.f}, s1 = {0.f,0.f,0.f,0.f};
        #pragma unroll 1
        for (int ss = 0; ss < 16; ++ss) {
            const float* p = pp + (((size_t)(g * 16 + ss)) << 12) + tid * 8;
            s0 += *(const f32x4*)p;
            s1 += *(const f32x4*)(p + 4);
        }
        s0[0] += bo0; s0[1] += bo1; s0[2] += bo0; s0[3] += bo1;
        s1[0] += bo0; s1[1] += bo1; s1[2] += bo0; s1[3] += bo1;
        *(f32x4*)(xls + tid * 8) = s0;
        *(f32x4*)(xls + tid * 8 + 4) = s1;
        if (s == 0) {
            float* ob = outp + (size_t)(m0 + tid * 4) * (2 * NSTEP) + (t - 1) * 2;
            *(float2*)(ob)             = make_float2(s0[0], s0[1]);
            *(float2*)(ob + 2 * NSTEP) = make_float2(s0[2], s0[3]);
            *(float2*)(ob + 4 * NSTEP) = make_float2(s1[0], s1[1]);
            *(float2*)(ob + 6 * NSTEP) = make_float2(s1[2], s1[3]);
        }
    }

    // staging decompose (r10 verbatim): LDS byte = p*8192 + tid*16 -> ks = p*4 + (tid>>7)
    const int st_l15 = tid & 15, st_lg = (tid >> 4) & 3, st_rh = (tid >> 6) & 1, st_kq = tid >> 7;
    const int st_grow = st_rh * 16 + st_l15;

    // prologue: stage chunk 0, load nv = chunk 1, prefetch c(ch0)
    uint4 nv[4];
    #pragma unroll
    for (int p = 0; p < 4; ++p) {
        int ks = p * 4 + st_kq;
        uint4 v = *(const uint4*)(h1R + (size_t)(m0 + st_grow) * HID + ks * 32 + st_lg * 8);
        *(uint4*)((char*)Ab + p * 8192 + tid * 16) = v;
    }
    #pragma unroll
    for (int p = 0; p < 4; ++p) {
        int ks = p * 4 + st_kq;
        nv[p] = *(const uint4*)(h1R + (size_t)(m0 + 32 + st_grow) * HID + ks * 32 + st_lg * 8);
    }
    unsigned cpr = *(const unsigned*)(c1s + (size_t)(m0 + erow) * HID + s * 32 + ejp * 2);
    __syncthreads();

    #pragma unroll 1
    for (int ch = 0; ch < 64; ++ch) {
        // ---- phase A: GEMM + gl partial writes ----
        f32x4 acc[2][2];
        #pragma unroll
        for (int j = 0; j < 2; ++j)
            #pragma unroll
            for (int rh = 0; rh < 2; ++rh) { acc[j][rh][0]=0.f; acc[j][rh][1]=0.f; acc[j][rh][2]=0.f; acc[j][rh][3]=0.f; }
        #pragma unroll
        for (int ksl = 0; ksl < 8; ++ksl) {
            int ks = kh * 8 + ksl;
            s16x8 a0 = *(const s16x8*)((const char*)Ab + ks * 2048 + lane * 16);
            s16x8 a1 = *(const s16x8*)((const char*)Ab + ks * 2048 + 1024 + lane * 16);
            #pragma unroll
            for (int j = 0; j < 2; ++j) {
                acc[j][0] = __builtin_amdgcn_mfma_f32_16x16x32_bf16(a0, bw[j][ksl], acc[j][0], 0, 0, 0);
                acc[j][1] = __builtin_amdgcn_mfma_f32_16x16x32_bf16(a1, bw[j][ksl], acc[j][1], 0, 0, 0);
            }
        }
        #pragma unroll
        for (int j = 0; j < 2; ++j) {
            int col = (cg * 2 + j) * 16 + l15;
            #pragma unroll
            for (int rh = 0; rh < 2; ++rh)
                #pragma unroll
                for (int r = 0; r < 4; ++r)
                    glf[kh * 4224 + (rh * 16 + lg * 4 + r) * 132 + col] = acc[j][rh][r];
        }
        __syncthreads();   // (A) gl complete; Ab reads done

        // ---- phase B: stage next chunk, reload nv, epilogue ----
        if (ch < 63) {
            #pragma unroll
            for (int p = 0; p < 4; ++p)
                *(uint4*)((char*)Ab + p * 8192 + tid * 16) = nv[p];
        }
        if (ch < 62) {
            #pragma unroll
            for (int p = 0; p < 4; ++p) {
                int ks = p * 4 + st_kq;
                nv[p] = *(const uint4*)(h1R + (size_t)(m0 + (ch + 2) * 32 + st_grow) * HID + ks * 32 + st_lg * 8);
            }
        }
        unsigned cnx = 0;
        if (ch < 63)
            cnx = *(const unsigned*)(c1s + (size_t)(m0 + (ch + 1) * 32 + erow) * HID + s * 32 + ejp * 2);

        {
            int grow = ch * 32 + erow;
            int m = m0 + grow;
            float x0 = xls[grow * 2 + 0], x1 = xls[grow * 2 + 1];
            int gbase = erow * 132 + ejp * 8;
            f32x4 qa = *(const f32x4*)&glf[gbase];
            qa += *(const f32x4*)&glf[4224 + gbase];
            f32x4 qb = *(const f32x4*)&glf[gbase + 4];
            qb += *(const f32x4*)&glf[4224 + gbase + 4];

            float cold0 = bf2f(cpr & 0xffffu), cold1 = bf2f(cpr >> 16);
            float i0 = sigm(qa[0] + b1v[0] + x0 * wiA[0] + x1 * wiB[0]);
            float f0 = sigm(qa[1] + b1v[2] + x0 * wiA[2] + x1 * wiB[2]);
            float g0 = tanh_(qa[2] + b1v[4] + x0 * wiA[4] + x1 * wiB[4]);
            float o0 = sigm(qa[3] + b1v[6] + x0 * wiA[6] + x1 * wiB[6]);
            float cn0 = f0 * cold0 + i0 * g0;
            float hn0 = o0 * tanh_(cn0);
            float i1 = sigm(qb[0] + b1v[1] + x0 * wiA[1] + x1 * wiB[1]);
            float f1 = sigm(qb[1] + b1v[3] + x0 * wiA[3] + x1 * wiB[3]);
            float g1 = tanh_(qb[2] + b1v[5] + x0 * wiA[5] + x1 * wiB[5]);
            float o1 = sigm(qb[3] + b1v[7] + x0 * wiA[7] + x1 * wiB[7]);
            float cn1 = f1 * cold1 + i1 * g1;
            float hn1 = o1 * tanh_(cn1);
            size_t cix = (size_t)m * HID + s * 32 + ejp * 2;
            *(unsigned*)(c1s + cix) = (unsigned)f2bf(cn0) | ((unsigned)f2bf(cn1) << 16);
            *(unsigned*)(h1W + cix) = (unsigned)f2bf(hn0) | ((unsigned)f2bf(hn1) << 16);
        }
        cpr = cnx;
        __syncthreads();   // (B) Ab staged; gl consumed
    }
}

// ---------------- layer-2: waves = 4 ct-pairs x 2 kh (K=1024); 2-copy gl merge ----------------
__global__ __launch_bounds__(TPB, 2) void l2_kernel(
    const unsigned short* __restrict__ h1C, const unsigned short* __restrict__ h2R,
    unsigned short* __restrict__ h2W, unsigned short* __restrict__ c2s,
    float* __restrict__ pp,
    const unsigned short* __restrict__ PW2, const float* __restrict__ b2,
    const float* __restrict__ w_out)
{
    __shared__ __align__(16) unsigned short Ab[32768];   // 64 KB single buffer
    __shared__ __align__(16) float glf[2 * 4224];        // 33 KB

    const int tid = threadIdx.x, lane = tid & 63, w = tid >> 6;
    const int b = blockIdx.x;
    const int g = 2 * (b & 7) + (b >> 7);
    const int s = (b >> 3) & 15;
    const int m0 = g * 2048;
    const int l15 = lane & 15, lg = lane >> 4;
    const int cg = w >> 1, kh = w & 1;

    // B fragments: ct = cg*2+j, ks = kh*16+ksl  (64 VGPR)
    s16x8 bw[2][16];
    #pragma unroll
    for (int j = 0; j < 2; ++j)
        #pragma unroll
        for (int ksl = 0; ksl < 16; ++ksl)
            bw[j][ksl] = ((const s16x8*)PW2)[(((s * 8 + cg * 2 + j) * 32) + kh * 16 + ksl) * 64 + lane];

    const int erow = tid >> 4, ejp = tid & 15;
    float b2v[8];
    #pragma unroll
    for (int q = 0; q < 8; ++q) {
        int dj = q & 1, gq = q >> 1;
        b2v[q] = b2[gq * 512 + s * 32 + ejp * 2 + dj];
    }
    float woA0 = w_out[s * 32 + ejp * 2], woA1 = w_out[s * 32 + ejp * 2 + 1];
    float woB0 = w_out[512 + s * 32 + ejp * 2], woB1 = w_out[512 + s * 32 + ejp * 2 + 1];

    const int st_l15 = tid & 15, st_lg = (tid >> 4) & 3, st_rh = (tid >> 6) & 1, st_kq = tid >> 7;
    const int st_grow = st_rh * 16 + st_l15;

    uint4 nv[8];
    #pragma unroll
    for (int p = 0; p < 8; ++p) {
        int ks = p * 4 + st_kq;
        const unsigned short* src = (ks < 16) ? h1C : h2R;
        int kel = (ks < 16) ? ks : (ks - 16);
        uint4 v = *(const uint4*)(src + (size_t)(m0 + st_grow) * HID + kel * 32 + st_lg * 8);
        *(uint4*)((char*)Ab + p * 8192 + tid * 16) = v;
    }
    #pragma unroll
    for (int p = 0; p < 8; ++p) {
        int ks = p * 4 + st_kq;
        const unsigned short* src = (ks < 16) ? h1C : h2R;
        int kel = (ks < 16) ? ks : (ks - 16);
        nv[p] = *(const uint4*)(src + (size_t)(m0 + 32 + st_grow) * HID + kel * 32 + st_lg * 8);
    }
    unsigned cpr = *(const unsigned*)(c2s + (size_t)(m0 + erow) * HID + s * 32 + ejp * 2);
    __syncthreads();

    #pragma unroll 1
    for (int ch = 0; ch < 64; ++ch) {
        // ---- phase A ----
        f32x4 acc[2][2];
        #pragma unroll
        for (int j = 0; j < 2; ++j)
            #pragma unroll
            for (int rh = 0; rh < 2; ++rh) { acc[j][rh][0]=0.f; acc[j][rh][1]=0.f; acc[j][rh][2]=0.f; acc[j][rh][3]=0.f; }
        #pragma unroll
        for (int ksl = 0; ksl < 16; ++ksl) {
            int ks = kh * 16 + ksl;
            s16x8 a0 = *(const s16x8*)((const char*)Ab + ks * 2048 + lane * 16);
            s16x8 a1 = *(const s16x8*)((const char*)Ab + ks * 2048 + 1024 + lane * 16);
            #pragma unroll
            for (int j = 0; j < 2; ++j) {
                acc[j][0] = __builtin_amdgcn_mfma_f32_16x16x32_bf16(a0, bw[j][ksl], acc[j][0], 0, 0, 0);
                acc[j][1] = __builtin_amdgcn_mfma_f32_16x16x32_bf16(a1, bw[j][ksl], acc[j][1], 0, 0, 0);
            }
        }
        #pragma unroll
        for (int j = 0; j < 2; ++j) {
            int col = (cg * 2 + j) * 16 + l15;
            #pragma unroll
            for (int rh = 0; rh < 2; ++rh)
                #pragma unroll
                for (int r = 0; r < 4; ++r)
                    glf[kh * 4224 + (rh * 16 + lg * 4 + r) * 132 + col] = acc[j][rh][r];
        }
        __syncthreads();   // (A)

        // ---- phase B ----
        if (ch < 63) {
            #pragma unroll
            for (int p = 0; p < 8; ++p)
                *(uint4*)((char*)Ab + p * 8192 + tid * 16) = nv[p];
        }
        if (ch < 62) {
            #pragma unroll
            for (int p = 0; p < 8; ++p) {
                int ks = p * 4 + st_kq;
                const unsigned short* src = (ks < 16) ? h1C : h2R;
                int kel = (ks < 16) ? ks : (ks - 16);
                nv[p] = *(const uint4*)(src + (size_t)(m0 + (ch + 2) * 32 + st_grow) * HID + kel * 32 + st_lg * 8);
            }
        }
        unsigned cnx = 0;
        if (ch < 63)
            cnx = *(const unsigned*)(c2s + (size_t)(m0 + (ch + 1) * 32 + erow) * HID + s * 32 + ejp * 2);

        {
            int grow = ch * 32 + erow;
            int m = m0 + grow;
            int gbase = erow * 132 + ejp * 8;
            f32x4 qa = *(const f32x4*)&glf[gbase];
            qa += *(const f32x4*)&glf[4224 + gbase];
            f32x4 qb = *(const f32x4*)&glf[gbase + 4];
            qb += *(const f32x4*)&glf[4224 + gbase + 4];

            float cold0 = bf2f(cpr & 0xffffu), cold1 = bf2f(cpr >> 16);
            float i0 = sigm(qa[0] + b2v[0]);
            float f0 = sigm(qa[1] + b2v[2]);
            float g0 = tanh_(qa[2] + b2v[4]);
            float o0 = sigm(qa[3] + b2v[6]);
            float cn0 = f0 * cold0 + i0 * g0;
            float hn0 = o0 * tanh_(cn0);
            float i1 = sigm(qb[0] + b2v[1]);
            float f1 = sigm(qb[1] + b2v[3]);
            float g1 = tanh_(qb[2] + b2v[5]);
            float o1 = sigm(qb[3] + b2v[7]);
            float cn1 = f1 * cold1 + i1 * g1;
            float hn1 = o1 * tanh_(cn1);
            size_t cix = (size_t)m * HID + s * 32 + ejp * 2;
            *(unsigned*)(c2s + cix) = (unsigned)f2bf(cn0) | ((unsigned)f2bf(cn1) << 16);
            *(unsigned*)(h2W + cix) = (unsigned)f2bf(hn0) | ((unsigned)f2bf(hn1) << 16);

            float p0 = hn0 * woA0 + hn1 * woA1;
            float p1 = hn0 * woB0 + hn1 * woB1;
            #pragma unroll
            for (int d = 1; d < 16; d <<= 1) {
                p0 += __shfl_xor(p0, d, 16);
                p1 += __shfl_xor(p1, d, 16);
            }
            if (ejp == 0)
                *(float2*)(pp + (((size_t)(g * 16 + s)) << 12) + (size_t)grow * 2)
                    = make_float2(p0, p1);
        }
        cpr = cnx;
        __syncthreads();   // (B)
    }
}

// ---------------- final-step output ----------------
__global__ void tail_kernel(const float* __restrict__ pp, const float* __restrict__ b_out,
                            float* __restrict__ outp)
{
    int i = blockIdx.x * 256 + threadIdx.x;
    if (i < 65536) {
        int m = i >> 1, j = i & 1;
        int g = m >> 11;
        int idx = (m & 2047) * 2 + j;
        float sum = b_out[j];
        #pragma unroll 1
        for (int s = 0; s < 16; ++s)
            sum += pp[(((size_t)(g * 16 + s)) << 12) + idx];
        outp[(size_t)m * (2 * NSTEP) + (NSTEP - 1) * 2 + j] = sum;
    }
}

extern "C" void kernel_launch(void* const* d_in, const int* in_sizes, int n_in,
                              void* d_out, int out_size, void* d_ws, size_t ws_size,
                              hipStream_t stream)
{
    (void)in_sizes; (void)n_in; (void)out_size; (void)ws_size;
    const float* h        = (const float*)d_in[0];
    const float* w_init_h = (const float*)d_in[1];
    const float* b_init_h = (const float*)d_in[2];
    const float* w_init_c = (const float*)d_in[3];
    const float* b_init_c = (const float*)d_in[4];
    const float* w_ih0    = (const float*)d_in[5];
    const float* w_hh0    = (const float*)d_in[6];
    const float* b_ih0    = (const float*)d_in[7];
    const float* b_hh0    = (const float*)d_in[8];
    const float* w_ih1    = (const float*)d_in[9];
    const float* w_hh1    = (const float*)d_in[10];
    const float* b_ih1    = (const float*)d_in[11];
    const float* b_hh1    = (const float*)d_in[12];
    const float* w_out    = (const float*)d_in[13];
    const float* b_out    = (const float*)d_in[14];
    float* out = (float*)d_out;

    char* ws = (char*)d_ws;
    unsigned short* h1s[2] = { (unsigned short*)(ws + 0),
                               (unsigned short*)(ws + 33554432) };
    unsigned short* h2s[2] = { (unsigned short*)(ws + 67108864),
                               (unsigned short*)(ws + 100663296) };
    unsigned short* c1s = (unsigned short*)(ws + 134217728);
    unsigned short* c2s = (unsigned short*)(ws + 167772160);
    float* pp           = (float*)(ws + 201326592);   // 4 MB
    unsigned short* PW1 = (unsigned short*)(ws + 205520896);
    unsigned short* PW2 = (unsigned short*)(ws + 207618048);
    unsigned short* PI  = (unsigned short*)(ws + 211812352);
    float* b1 = (float*)(ws + 212860928);
    float* b2 = (float*)(ws + 212869120);

    pack_kernel<<<14352, 256, 0, stream>>>(w_hh0, w_ih1, w_hh1, w_init_h, w_init_c,
                                           b_ih0, b_hh0, b_ih1, b_hh1, PW1, PW2, PI, b1, b2);
    init_kernel<<<32768 / BMI, TPB, 0, stream>>>(h, PI, b_init_h, b_init_c,
                                                 h1s[1], h2s[1], c1s, c2s);
    for (int t = 0; t < NSTEP; ++t) {
        const unsigned short* h1R = h1s[(t + 1) & 1];
        unsigned short* h1W = h1s[t & 1];
        const unsigned short* h2R = h2s[(t + 1) & 1];
        unsigned short* h2W = h2s[t & 1];
        l1_kernel<<<256, TPB, 0, stream>>>(h1R, h1W, c1s, pp, out, PW1, b1, w_ih0, b_out, t);
        l2_kernel<<<256, TPB, 0, stream>>>(h1W, h2R, h2W, c2s, pp, PW2, b2, w_out);
    }
    tail_kernel<<<256, 256, 0, stream>>>(pp, b_out, out);
}

// Round 13
// 35891.449 us; speedup vs baseline: 1.1278x; 1.0545x over previous
//
#include <hip/hip_runtime.h>

#define HID    512
#define TPB    512
#define TPB2   1024
#define NSTEP  60
#define BMI    64

using f32x4 = __attribute__((ext_vector_type(4))) float;
using s16x8 = __attribute__((ext_vector_type(8))) short;

__device__ __forceinline__ unsigned short f2bf(float f) {
    unsigned u = __builtin_bit_cast(unsigned, f);
    u += 0x7fffu + ((u >> 16) & 1u);
    return (unsigned short)(u >> 16);
}
__device__ __forceinline__ float bf2f(unsigned u) {
    return __builtin_bit_cast(float, u << 16);
}
__device__ __forceinline__ float sigm(float x) { return 1.0f / (1.0f + __expf(-x)); }
__device__ __forceinline__ float tanh_(float x) { return 1.0f - 2.0f / (__expf(2.0f * x) + 1.0f); }

// ---------------- weight packing (identical to r10/r12 — verified) ----------------
// Col mapping inside each 16-col MFMA tile: col c -> gate (c&3), unit ct*4+(c>>2).
__global__ void pack_kernel(const float* __restrict__ w_hh0, const float* __restrict__ w_ih1,
                            const float* __restrict__ w_hh1, const float* __restrict__ w_init_h,
                            const float* __restrict__ w_init_c,
                            const float* __restrict__ b_ih0, const float* __restrict__ b_hh0,
                            const float* __restrict__ b_ih1, const float* __restrict__ b_hh1,
                            unsigned short* __restrict__ PW1, unsigned short* __restrict__ PW2,
                            unsigned short* __restrict__ PI,
                            float* __restrict__ b1, float* __restrict__ b2)
{
    int idx = blockIdx.x * 256 + threadIdx.x;
    if (idx < 1048576) {
        int el = idx & 511, fr = idx >> 9;
        int ks = fr & 15, ct = (fr >> 4) & 7, s = fr >> 7;
        int lane = el >> 3, e = el & 7;
        int l15 = lane & 15;
        int gcol = (l15 & 3) * 512 + s * 32 + ct * 4 + (l15 >> 2);
        int k = ks * 32 + (lane >> 4) * 8 + e;
        PW1[idx] = f2bf(w_hh0[gcol * 512 + k]);
        return;
    }
    int i2 = idx - 1048576;
    if (i2 >= 0 && i2 < 2097152) {
        int el = i2 & 511, fr = i2 >> 9;
        int ks = fr & 31, ct = (fr >> 5) & 7, s = fr >> 8;
        int lane = el >> 3, e = el & 7;
        int l15 = lane & 15;
        int gcol = (l15 & 3) * 512 + s * 32 + ct * 4 + (l15 >> 2);
        int kk = (ks & 15) * 32 + (lane >> 4) * 8 + e;
        float v = (ks < 16) ? w_ih1[gcol * 512 + kk] : w_hh1[gcol * 512 + kk];
        PW2[i2] = f2bf(v);
        return;
    }
    int i3 = idx - (1048576 + 2097152);
    if (i3 >= 0 && i3 < 524288) {
        int el = i3 & 511, fr = i3 >> 9;
        int ks = fr & 15, tile = fr >> 4;
        int s = tile >> 5, c = tile & 31;
        int lane = el >> 3, e = el & 7;
        int n = c * 16 + (lane & 15);
        int k = ks * 32 + (lane >> 4) * 8 + e;
        float v = s ? w_init_c[n * 512 + k] : w_init_h[n * 512 + k];
        PI[i3] = f2bf(v);
        return;
    }
    int i4 = idx - (1048576 + 2097152 + 524288);
    if (i4 >= 0 && i4 < 2048) b1[i4] = b_ih0[i4] + b_hh0[i4];
    else if (i4 >= 2048 && i4 < 4096) b2[i4 - 2048] = b_ih1[i4 - 2048] + b_hh1[i4 - 2048];
}

// ---------------- init (r10/r12 version, interleaved [m][512] state — verified) ----------------
__global__ __launch_bounds__(TPB, 2) void init_kernel(
    const float* __restrict__ hin, const unsigned short* __restrict__ PI,
    const float* __restrict__ b_init_h, const float* __restrict__ b_init_c,
    unsigned short* __restrict__ h1s, unsigned short* __restrict__ h2s,
    unsigned short* __restrict__ c1s, unsigned short* __restrict__ c2s)
{
    __shared__ unsigned short bufA[BMI * HID];
    const int tid = threadIdx.x, lane = tid & 63, wave = tid >> 6;
    const int m0 = blockIdx.x * BMI;
    const int l15 = lane & 15, lg = lane >> 4;
    const int swz = (lane & 7) << 4;

    for (int j = 0; j < 16; ++j) {
        int e = tid * 4 + j * 2048;
        int row = e >> 9, col = e & 511;
        float4 v = *(const float4*)(hin + (size_t)(m0 + row) * HID + col);
        ushort4 w;
        w.x = f2bf(v.x); w.y = f2bf(v.y); w.z = f2bf(v.z); w.w = f2bf(v.w);
        int L = (row * 1024 + col * 2) ^ ((row & 7) << 4);
        *(ushort4*)((char*)bufA + L) = w;
    }
    __syncthreads();

    #pragma unroll 1
    for (int cc = 0; cc < 4; ++cc) {
        int c = wave * 4 + cc;
        int nc = c * 16 + l15;
        f32x4 acc[4][2];
        #pragma unroll
        for (int rt = 0; rt < 4; ++rt)
            #pragma unroll
            for (int s = 0; s < 2; ++s)
                #pragma unroll
                for (int r = 0; r < 4; ++r) acc[rt][s][r] = 0.0f;

        #pragma unroll
        for (int ks = 0; ks < 16; ++ks) {
            s16x8 a[4];
            #pragma unroll
            for (int rt = 0; rt < 4; ++rt) {
                int ao = (rt * 16 + l15) * 1024 + ((ks * 64 + lg * 16) ^ swz);
                a[rt] = *(const s16x8*)((const char*)bufA + ao);
            }
            #pragma unroll
            for (int s = 0; s < 2; ++s) {
                s16x8 b = ((const s16x8*)PI)[((s * 32 + c) * 16 + ks) * 64 + lane];
                #pragma unroll
                for (int rt = 0; rt < 4; ++rt)
                    acc[rt][s] = __builtin_amdgcn_mfma_f32_16x16x32_bf16(a[rt], b, acc[rt][s], 0, 0, 0);
            }
        }
        float bh = b_init_h[nc], bc = b_init_c[nc];
        #pragma unroll
        for (int rt = 0; rt < 4; ++rt)
            #pragma unroll
            for (int r = 0; r < 4; ++r) {
                int m = m0 + rt * 16 + lg * 4 + r;
                float hv = acc[rt][0][r] + bh;
                float cv = acc[rt][1][r] + bc;
                unsigned short hb = f2bf(hv);
                size_t o = (size_t)m * HID + nc;
                h1s[o] = hb; h2s[o] = hb;
                c1s[o] = f2bf(cv); c2s[o] = f2bf(cv);
            }
    }
}

// ---------------- layer-1: 1024 threads = 16 waves (8 ct x 2 kh); 2 barriers/chunk ----------------
__global__ __launch_bounds__(TPB2, 4) void l1_kernel(
    const unsigned short* __restrict__ h1R, unsigned short* __restrict__ h1W,
    unsigned short* __restrict__ c1s, const float* __restrict__ pp,
    float* __restrict__ outp, const unsigned short* __restrict__ PW1,
    const float* __restrict__ b1, const float* __restrict__ w_ih0,
    const float* __restrict__ b_out, int t)
{
    __shared__ __align__(16) unsigned short Ab[16384];   // 32 KB: [ks16][rh2][lg4][l15][16B]
    __shared__ __align__(16) float glf[2 * 4224];        // 33 KB: [kh][row32][col 132pad]
    __shared__ __align__(16) float xls[4096];            // 16 KB

    const int tid = threadIdx.x, lane = tid & 63, w = tid >> 6;
    const int b = blockIdx.x;
    const int g = 2 * (b & 7) + (b >> 7);
    const int s = (b >> 3) & 15;
    const int m0 = g * 2048;
    const int l15 = lane & 15, lg = lane >> 4;
    const int ct = w & 7, kh = w >> 3;

    // B fragments: 1 ct-tile, K-half kh (32 VGPR)
    s16x8 bw[8];
    #pragma unroll
    for (int ksl = 0; ksl < 8; ++ksl)
        bw[ksl] = ((const s16x8*)PW1)[(((s * 8 + ct) * 16) + kh * 8 + ksl) * 64 + lane];

    // epilogue role: 1 unit/thread: row = tid>>5 (0..31), u = tid&31
    const int erow = tid >> 5, eu = tid & 31;
    float b1v[4], wiA[4], wiB[4];
    #pragma unroll
    for (int k = 0; k < 4; ++k) {
        int gcol = k * 512 + s * 32 + eu;
        b1v[k] = b1[gcol];
        wiA[k] = w_ih0[gcol * 2 + 0];
        wiB[k] = w_ih0[gcol * 2 + 1];
    }
    float bo0 = b_out[0], bo1 = b_out[1];

    // ---- reduce prev-step partials -> xls; write out[:,t-1] ----
    if (t == 0) {
        #pragma unroll
        for (int i = 0; i < 4; ++i) xls[tid * 4 + i] = 0.0f;
    } else {
        f32x4 s0 = {0.f,0.f,0.f,0.f};
        #pragma unroll 1
        for (int ss = 0; ss < 16; ++ss)
            s0 += *(const f32x4*)(pp + (((size_t)(g * 16 + ss)) << 12) + tid * 4);
        s0[0] += bo0; s0[1] += bo1; s0[2] += bo0; s0[3] += bo1;
        *(f32x4*)(xls + tid * 4) = s0;
        if (s == 0) {
            float* ob = outp + (size_t)(m0 + tid * 2) * (2 * NSTEP) + (t - 1) * 2;
            *(float2*)(ob)             = make_float2(s0[0], s0[1]);
            *(float2*)(ob + 2 * NSTEP) = make_float2(s0[2], s0[3]);
        }
    }

    // staging: thread -> slot; LDS byte = p*16384 + tid*16; ks = p*8 + (tid>>7)
    const int st_l15 = tid & 15, st_lg = (tid >> 4) & 3, st_rh = (tid >> 6) & 1, st_kb = tid >> 7;
    const int st_grow = st_rh * 16 + st_l15;

    // prologue: stage chunk 0, nv = chunk 1, prefetch c(ch0)
    uint4 nv[2];
    #pragma unroll
    for (int p = 0; p < 2; ++p) {
        int ks = p * 8 + st_kb;
        uint4 v = *(const uint4*)(h1R + (size_t)(m0 + st_grow) * HID + ks * 32 + st_lg * 8);
        *(uint4*)((char*)Ab + p * 16384 + tid * 16) = v;
    }
    #pragma unroll
    for (int p = 0; p < 2; ++p) {
        int ks = p * 8 + st_kb;
        nv[p] = *(const uint4*)(h1R + (size_t)(m0 + 32 + st_grow) * HID + ks * 32 + st_lg * 8);
    }
    unsigned short cpr = c1s[(size_t)(m0 + erow) * HID + s * 32 + eu];
    __syncthreads();

    #pragma unroll 1
    for (int ch = 0; ch < 64; ++ch) {
        // ---- phase A: GEMM + glf write ----
        f32x4 acc[2];
        acc[0][0]=0.f; acc[0][1]=0.f; acc[0][2]=0.f; acc[0][3]=0.f;
        acc[1][0]=0.f; acc[1][1]=0.f; acc[1][2]=0.f; acc[1][3]=0.f;
        #pragma unroll
        for (int ksl = 0; ksl < 8; ++ksl) {
            int ks = kh * 8 + ksl;
            s16x8 a0 = *(const s16x8*)((const char*)Ab + ks * 2048 + lane * 16);
            s16x8 a1 = *(const s16x8*)((const char*)Ab + ks * 2048 + 1024 + lane * 16);
            acc[0] = __builtin_amdgcn_mfma_f32_16x16x32_bf16(a0, bw[ksl], acc[0], 0, 0, 0);
            acc[1] = __builtin_amdgcn_mfma_f32_16x16x32_bf16(a1, bw[ksl], acc[1], 0, 0, 0);
        }
        {
            int col = ct * 16 + l15;
            #pragma unroll
            for (int rh = 0; rh < 2; ++rh)
                #pragma unroll
                for (int r = 0; r < 4; ++r)
                    glf[kh * 4224 + (rh * 16 + lg * 4 + r) * 132 + col] = acc[rh][r];
        }
        __syncthreads();   // (A) glf complete; Ab reads done

        // ---- phase B: stage next, reload nv, epilogue ----
        if (ch < 63) {
            #pragma unroll
            for (int p = 0; p < 2; ++p)
                *(uint4*)((char*)Ab + p * 16384 + tid * 16) = nv[p];
        }
        if (ch < 62) {
            #pragma unroll
            for (int p = 0; p < 2; ++p) {
                int ks = p * 8 + st_kb;
                nv[p] = *(const uint4*)(h1R + (size_t)(m0 + (ch + 2) * 32 + st_grow) * HID + ks * 32 + st_lg * 8);
            }
        }
        unsigned short cnx = 0;
        if (ch < 63)
            cnx = c1s[(size_t)(m0 + (ch + 1) * 32 + erow) * HID + s * 32 + eu];

        {
            int grow = ch * 32 + erow;
            float x0 = xls[grow * 2 + 0], x1 = xls[grow * 2 + 1];
            int base = erow * 132 + (eu >> 2) * 16 + (eu & 3) * 4;
            f32x4 q = *(const f32x4*)&glf[base];
            q += *(const f32x4*)&glf[4224 + base];
            float iv = sigm(q[0] + b1v[0] + x0 * wiA[0] + x1 * wiB[0]);
            float fv = sigm(q[1] + b1v[1] + x0 * wiA[1] + x1 * wiB[1]);
            float gv = tanh_(q[2] + b1v[2] + x0 * wiA[2] + x1 * wiB[2]);
            float ov = sigm(q[3] + b1v[3] + x0 * wiA[3] + x1 * wiB[3]);
            float cold = bf2f(cpr);
            float cn = fv * cold + iv * gv;
            float hn = ov * tanh_(cn);
            size_t cix = (size_t)(m0 + grow) * HID + s * 32 + eu;
            c1s[cix] = f2bf(cn);
            h1W[cix] = f2bf(hn);
        }
        cpr = cnx;
        __syncthreads();   // (B) Ab staged; glf consumed
    }
}

// ---------------- layer-2: 1024 threads = 16 waves (8 ct x 2 kh), K=1024 ----------------
__global__ __launch_bounds__(TPB2, 4) void l2_kernel(
    const unsigned short* __restrict__ h1C, const unsigned short* __restrict__ h2R,
    unsigned short* __restrict__ h2W, unsigned short* __restrict__ c2s,
    float* __restrict__ pp,
    const unsigned short* __restrict__ PW2, const float* __restrict__ b2,
    const float* __restrict__ w_out)
{
    __shared__ __align__(16) unsigned short Ab[32768];   // 64 KB: [ks32][rh2][lg4][l15][16B]
    __shared__ __align__(16) float glf[2 * 4224];        // 33 KB

    const int tid = threadIdx.x, lane = tid & 63, w = tid >> 6;
    const int b = blockIdx.x;
    const int g = 2 * (b & 7) + (b >> 7);
    const int s = (b >> 3) & 15;
    const int m0 = g * 2048;
    const int l15 = lane & 15, lg = lane >> 4;
    const int ct = w & 7, kh = w >> 3;

    // B fragments: 1 ct-tile, K-half kh (64 VGPR)
    s16x8 bw[16];
    #pragma unroll
    for (int ksl = 0; ksl < 16; ++ksl)
        bw[ksl] = ((const s16x8*)PW2)[(((s * 8 + ct) * 32) + kh * 16 + ksl) * 64 + lane];

    const int erow = tid >> 5, eu = tid & 31;
    float b2v[4];
    #pragma unroll
    for (int k = 0; k < 4; ++k) b2v[k] = b2[k * 512 + s * 32 + eu];
    const float wo0 = w_out[s * 32 + eu], wo1 = w_out[512 + s * 32 + eu];

    const int st_l15 = tid & 15, st_lg = (tid >> 4) & 3, st_rh = (tid >> 6) & 1, st_kb = tid >> 7;
    const int st_grow = st_rh * 16 + st_l15;

    uint4 nv[4];
    #pragma unroll
    for (int p = 0; p < 4; ++p) {
        int ks = p * 8 + st_kb;
        const unsigned short* src = (ks < 16) ? h1C : h2R;
        int kel = (ks < 16) ? ks : (ks - 16);
        uint4 v = *(const uint4*)(src + (size_t)(m0 + st_grow) * HID + kel * 32 + st_lg * 8);
        *(uint4*)((char*)Ab + p * 16384 + tid * 16) = v;
    }
    #pragma unroll
    for (int p = 0; p < 4; ++p) {
        int ks = p * 8 + st_kb;
        const unsigned short* src = (ks < 16) ? h1C : h2R;
        int kel = (ks < 16) ? ks : (ks - 16);
        nv[p] = *(const uint4*)(src + (size_t)(m0 + 32 + st_grow) * HID + kel * 32 + st_lg * 8);
    }
    unsigned short cpr = c2s[(size_t)(m0 + erow) * HID + s * 32 + eu];
    __syncthreads();

    #pragma unroll 1
    for (int ch = 0; ch < 64; ++ch) {
        // ---- phase A ----
        f32x4 acc[2];
        acc[0][0]=0.f; acc[0][1]=0.f; acc[0][2]=0.f; acc[0][3]=0.f;
        acc[1][0]=0.f; acc[1][1]=0.f; acc[1][2]=0.f; acc[1][3]=0.f;
        #pragma unroll
        for (int ksl = 0; ksl < 16; ++ksl) {
            int ks = kh * 16 + ksl;
            s16x8 a0 = *(const s16x8*)((const char*)Ab + ks * 2048 + lane * 16);
            s16x8 a1 = *(const s16x8*)((const char*)Ab + ks * 2048 + 1024 + lane * 16);
            acc[0] = __builtin_amdgcn_mfma_f32_16x16x32_bf16(a0, bw[ksl], acc[0], 0, 0, 0);
            acc[1] = __builtin_amdgcn_mfma_f32_16x16x32_bf16(a1, bw[ksl], acc[1], 0, 0, 0);
        }
        {
            int col = ct * 16 + l15;
            #pragma unroll
            for (int rh = 0; rh < 2; ++rh)
                #pragma unroll
                for (int r = 0; r < 4; ++r)
                    glf[kh * 4224 + (rh * 16 + lg * 4 + r) * 132 + col] = acc[rh][r];
        }
        __syncthreads();   // (A)

        // ---- phase B ----
        if (ch < 63) {
            #pragma unroll
            for (int p = 0; p < 4; ++p)
                *(uint4*)((char*)Ab + p * 16384 + tid * 16) = nv[p];
        }
        if (ch < 62) {
            #pragma unroll
            for (int p = 0; p < 4; ++p) {
                int ks = p * 8 + st_kb;
                const unsigned short* src = (ks < 16) ? h1C : h2R;
                int kel = (ks < 16) ? ks : (ks - 16);
                nv[p] = *(const uint4*)(src + (size_t)(m0 + (ch + 2) * 32 + st_grow) * HID + kel * 32 + st_lg * 8);
            }
        }
        unsigned short cnx = 0;
        if (ch < 63)
            cnx = c2s[(size_t)(m0 + (ch + 1) * 32 + erow) * HID + s * 32 + eu];

        {
            int grow = ch * 32 + erow;
            int base = erow * 132 + (eu >> 2) * 16 + (eu & 3) * 4;
            f32x4 q = *(const f32x4*)&glf[base];
            q += *(const f32x4*)&glf[4224 + base];
            float iv = sigm(q[0] + b2v[0]);
            float fv = sigm(q[1] + b2v[1]);
            float gv = tanh_(q[2] + b2v[2]);
            float ov = sigm(q[3] + b2v[3]);
            float cold = bf2f(cpr);
            float cn = fv * cold + iv * gv;
            float hn = ov * tanh_(cn);
            size_t cix = (size_t)(m0 + grow) * HID + s * 32 + eu;
            c2s[cix] = f2bf(cn);
            h2W[cix] = f2bf(hn);

            // output partial: reduce over the 32 units of this row (width-32 groups = rows)
            float p0 = hn * wo0, p1 = hn * wo1;
            #pragma unroll
            for (int d = 1; d < 32; d <<= 1) {
                p0 += __shfl_xor(p0, d, 32);
                p1 += __shfl_xor(p1, d, 32);
            }
            if (eu == 0)
                *(float2*)(pp + (((size_t)(g * 16 + s)) << 12) + (size_t)grow * 2)
                    = make_float2(p0, p1);
        }
        cpr = cnx;
        __syncthreads();   // (B)
    }
}

// ---------------- final-step output ----------------
__global__ void tail_kernel(const float* __restrict__ pp, const float* __restrict__ b_out,
                            float* __restrict__ outp)
{
    int i = blockIdx.x * 256 + threadIdx.x;
    if (i < 65536) {
        int m = i >> 1, j = i & 1;
        int g = m >> 11;
        int idx = (m & 2047) * 2 + j;
        float sum = b_out[j];
        #pragma unroll 1
        for (int s = 0; s < 16; ++s)
            sum += pp[(((size_t)(g * 16 + s)) << 12) + idx];
        outp[(size_t)m * (2 * NSTEP) + (NSTEP - 1) * 2 + j] = sum;
    }
}

extern "C" void kernel_launch(void* const* d_in, const int* in_sizes, int n_in,
                              void* d_out, int out_size, void* d_ws, size_t ws_size,
                              hipStream_t stream)
{
    (void)in_sizes; (void)n_in; (void)out_size; (void)ws_size;
    const float* h        = (const float*)d_in[0];
    const float* w_init_h = (const float*)d_in[1];
    const float* b_init_h = (const float*)d_in[2];
    const float* w_init_c = (const float*)d_in[3];
    const float* b_init_c = (const float*)d_in[4];
    const float* w_ih0    = (const float*)d_in[5];
    const float* w_hh0    = (const float*)d_in[6];
    const float* b_ih0    = (const float*)d_in[7];
    const float* b_hh0    = (const float*)d_in[8];
    const float* w_ih1    = (const float*)d_in[9];
    const float* w_hh1    = (const float*)d_in[10];
    const float* b_ih1    = (const float*)d_in[11];
    const float* b_hh1    = (const float*)d_in[12];
    const float* w_out    = (const float*)d_in[13];
    const float* b_out    = (const float*)d_in[14];
    float* out = (float*)d_out;

    char* ws = (char*)d_ws;
    unsigned short* h1s[2] = { (unsigned short*)(ws + 0),
                               (unsigned short*)(ws + 33554432) };
    unsigned short* h2s[2] = { (unsigned short*)(ws + 67108864),
                               (unsigned short*)(ws + 100663296) };
    unsigned short* c1s = (unsigned short*)(ws + 134217728);
    unsigned short* c2s = (unsigned short*)(ws + 167772160);
    float* pp           = (float*)(ws + 201326592);   // 4 MB
    unsigned short* PW1 = (unsigned short*)(ws + 205520896);
    unsigned short* PW2 = (unsigned short*)(ws + 207618048);
    unsigned short* PI  = (unsigned short*)(ws + 211812352);
    float* b1 = (float*)(ws + 212860928);
    float* b2 = (float*)(ws + 212869120);

    pack_kernel<<<14352, 256, 0, stream>>>(w_hh0, w_ih1, w_hh1, w_init_h, w_init_c,
                                           b_ih0, b_hh0, b_ih1, b_hh1, PW1, PW2, PI, b1, b2);
    init_kernel<<<32768 / BMI, TPB, 0, stream>>>(h, PI, b_init_h, b_init_c,
                                                 h1s[1], h2s[1], c1s, c2s);
    for (int t = 0; t < NSTEP; ++t) {
        const unsigned short* h1R = h1s[(t + 1) & 1];
        unsigned short* h1W = h1s[t & 1];
        const unsigned short* h2R = h2s[(t + 1) & 1];
        unsigned short* h2W = h2s[t & 1];
        l1_kernel<<<256, TPB2, 0, stream>>>(h1R, h1W, c1s, pp, out, PW1, b1, w_ih0, b_out, t);
        l2_kernel<<<256, TPB2, 0, stream>>>(h1W, h2R, h2W, c2s, pp, PW2, b2, w_out);
    }
    tail_kernel<<<256, 256, 0, stream>>>(pp, b_out, out);
}